// Round 9
// baseline (170.918 us; speedup 1.0000x reference)
//
#include <hip/hip_runtime.h>

// B=4, C=256, CR=64, H=W=64, K=7, KK=49, GROUPS=16, GC=16
#define BN_EPS 1e-5f

typedef __bf16 bf16_t;
typedef __bf16 bf16x8 __attribute__((ext_vector_type(8)));
typedef __bf16 bf16x4 __attribute__((ext_vector_type(4)));
typedef __bf16 bf16x2 __attribute__((ext_vector_type(2)));
typedef float  floatx4 __attribute__((ext_vector_type(4)));

#define MFMA16(a, b, c) __builtin_amdgcn_mfma_f32_16x16x32_bf16((a), (b), (c), 0, 0, 0)

#define XT_OFF 0   // ws: xT = 16384 px x 64 ch bf16 = 2 MB

// ---------------------------------------------------------------------------
// K1 conv1: one block per (b,h). BN-fold in-block; LDS transpose of guide;
// MFMA x[64o][64p] = w1s . gTs; +bias, ReLU; store xT[bp][o] c-contiguous.
// ---------------------------------------------------------------------------
#define GTP 264
#define W1P 264

__global__ __launch_bounds__(256) void conv1_k(
    const float* __restrict__ guide, const float* __restrict__ w1,
    const float* __restrict__ gamma, const float* __restrict__ beta,
    const float* __restrict__ mean,  const float* __restrict__ var,
    bf16_t* __restrict__ xT)
{
    __shared__ __attribute__((aligned(16))) bf16_t gTs[64 * GTP];  // 33.8 KB
    __shared__ __attribute__((aligned(16))) bf16_t w1s[64 * W1P];  // 33.8 KB
    const int b = blockIdx.x >> 6, h = blockIdx.x & 63;
    const int t = threadIdx.x;

#pragma unroll
    for (int i = 0; i < 16; ++i) {
        const int idx = i * 256 + t;
        const int o = idx >> 6, cq = idx & 63;
        const float inv = gamma[o] * rsqrtf(var[o] + BN_EPS);
        const float4 v = *(const float4*)(w1 + o * 256 + cq * 4);
        bf16_t* d = &w1s[o * W1P + cq * 4];
        d[0] = (bf16_t)(v.x * inv); d[1] = (bf16_t)(v.y * inv);
        d[2] = (bf16_t)(v.z * inv); d[3] = (bf16_t)(v.w * inv);
    }
    const float* gsrc = guide + (size_t)b * 256 * 4096 + h * 64;
#pragma unroll
    for (int i = 0; i < 32; ++i) {
        const int idx = i * 256 + t;
        const int c2 = idx >> 6, p = idx & 63;
        const float g0 = gsrc[(size_t)(2 * c2) * 4096 + p];
        const float g1 = gsrc[(size_t)(2 * c2 + 1) * 4096 + p];
        bf16x2 pk; pk[0] = (bf16_t)g0; pk[1] = (bf16_t)g1;
        *(bf16x2*)&gTs[p * GTP + 2 * c2] = pk;
    }
    __syncthreads();

    const int wv = t >> 6, ln = t & 63, l15 = ln & 15, q = ln >> 4;
    floatx4 acc[4] = {};
    const bf16_t* ap = &w1s[(wv * 16 + l15) * W1P];
#pragma unroll
    for (int ks = 0; ks < 8; ++ks) {
        const bf16x8 a = *(const bf16x8*)(ap + ks * 32 + q * 8);
#pragma unroll
        for (int nt = 0; nt < 4; ++nt) {
            const bf16x8 bb = *(const bf16x8*)&gTs[(nt * 16 + l15) * GTP + ks * 32 + q * 8];
            acc[nt] = MFMA16(a, bb, acc[nt]);
        }
    }
    float bi[4];
#pragma unroll
    for (int j = 0; j < 4; ++j) {
        const int o = wv * 16 + q * 4 + j;
        const float iv = gamma[o] * rsqrtf(var[o] + BN_EPS);
        bi[j] = beta[o] - mean[o] * iv;
    }
#pragma unroll
    for (int nt = 0; nt < 4; ++nt) {
        const int p = nt * 16 + l15;
        bf16x4 v;
#pragma unroll
        for (int j = 0; j < 4; ++j) v[j] = (bf16_t)fmaxf(acc[nt][j] + bi[j], 0.f);
        *(bf16x4*)(xT + ((size_t)(b * 64 + h) * 64 + p) * 64 + wv * 16 + q * 4) = v;
    }
}

// ---------------------------------------------------------------------------
// K2 conv2+agg fused: block = (g, b, h-pair); blockIdx = (b*32+hp)*16 + g.
//  fs2: bf16 feature tile [16ch][8 rows][72] (pads zeroed) = 18.4 KB
//  wgs: bf16 dyn-weight tile [49k][136]                     = 13.3 KB
//  total 31.7 KB -> 5 blocks/CU (launch_bounds(256,5)).
//  Residual float4s pre-loaded from global BEFORE the barrier (exact fp32).
// ---------------------------------------------------------------------------
#define FSR2 72    // bf16 row pitch: [4 pad][64 w][4 pad]
#define FSC2 576   // bf16 channel pitch = 8*72
#define WGP 136

__global__ __launch_bounds__(256, 5) void fused_k(
    const bf16_t* __restrict__ xT, const float* __restrict__ w2,
    const float* __restrict__ b2,  const float* __restrict__ feat,
    float* __restrict__ out)
{
    __shared__ __attribute__((aligned(16))) bf16_t fs2[16 * FSC2];  // 18.4 KB
    __shared__ __attribute__((aligned(16))) bf16_t wgs[49 * WGP];   // 13.3 KB

    const int g = blockIdx.x & 15;
    const int rest = blockIdx.x >> 4;
    const int b = rest >> 5, hp = rest & 31;
    const int h0 = hp * 2;
    const int t = threadIdx.x;
    const int wv = t >> 6, ln = t & 63, l15 = ln & 15, q = ln >> 4;

    // agg-thread mapping (also used for residual preload)
    const int wq = t & 15, r = (t >> 4) & 1, cp = t >> 5;   // cp in [0,8)
    const int w0 = wq * 4;
    const int ch0 = cp * 2;

    // ---- residual preload (fp32 exact), latency hidden across barrier ----
    float4 res[2];
#pragma unroll
    for (int c = 0; c < 2; ++c)
        res[c] = *(const float4*)(feat + ((size_t)(b * 256 + g * 16 + ch0 + c) * 64 + h0 + r) * 64 + w0);

    // ---- stage fs2: 1152 units of bf16x8; unit j covers w in [8j-4, 8j+3] ----
#pragma unroll
    for (int i = 0; i < 5; ++i) {
        const int u = i * 256 + t;
        if (u < 1152) {
            const int c = u / 72, rem = u - c * 72;
            const int rr = rem / 9, j = rem - rr * 9;
            const int hh = h0 - 3 + rr;
            const float* rp = feat + ((size_t)(b * 256 + g * 16 + c) * 64 + hh) * 64;
            float4 lo = {0.f, 0.f, 0.f, 0.f}, hi = {0.f, 0.f, 0.f, 0.f};
            const bool hok = (hh >= 0) && (hh < 64);
            if (hok && j >= 1) lo = *(const float4*)(rp + 8 * j - 4);
            if (hok && j <= 7) hi = *(const float4*)(rp + 8 * j);
            bf16x8 v;
            v[0] = (bf16_t)lo.x; v[1] = (bf16_t)lo.y; v[2] = (bf16_t)lo.z; v[3] = (bf16_t)lo.w;
            v[4] = (bf16_t)hi.x; v[5] = (bf16_t)hi.y; v[6] = (bf16_t)hi.z; v[7] = (bf16_t)hi.w;
            *(bf16x8*)&fs2[c * FSC2 + rr * FSR2 + j * 8] = v;
        }
    }

    // ---- MFMA: wg[49 x 128] = w2[g] . xT ; A-frags cvt fp32->bf16 in regs ----
    {
        floatx4 acc[4][2] = {};
        const bf16_t* brow = xT + ((size_t)(b * 64 + h0) * 64 + wv * 32) * 64;
#pragma unroll
        for (int ks = 0; ks < 2; ++ks) {
            bf16x8 bfr[2];
            bfr[0] = *(const bf16x8*)(brow + l15 * 64 + ks * 32 + q * 8);
            bfr[1] = *(const bf16x8*)(brow + (16 + l15) * 64 + ks * 32 + q * 8);
#pragma unroll
            for (int mt = 0; mt < 4; ++mt) {
                int row = mt * 16 + l15; if (row > 48) row = 48;
                const float* wp = w2 + (size_t)(g * 49 + row) * 64 + ks * 32 + q * 8;
                const float4 a0 = *(const float4*)(wp);
                const float4 a1 = *(const float4*)(wp + 4);
                bf16x8 a;
                a[0] = (bf16_t)a0.x; a[1] = (bf16_t)a0.y; a[2] = (bf16_t)a0.z; a[3] = (bf16_t)a0.w;
                a[4] = (bf16_t)a1.x; a[5] = (bf16_t)a1.y; a[6] = (bf16_t)a1.z; a[7] = (bf16_t)a1.w;
                acc[mt][0] = MFMA16(a, bfr[0], acc[mt][0]);
                acc[mt][1] = MFMA16(a, bfr[1], acc[mt][1]);
            }
        }
#pragma unroll
        for (int mt = 0; mt < 4; ++mt) {
#pragma unroll
            for (int j = 0; j < 4; ++j) {
                const int k = mt * 16 + q * 4 + j;
                if (k < 49) {
                    const float bias = b2[g * 49 + k];
                    wgs[k * WGP + wv * 32 + l15]      = (bf16_t)(acc[mt][0][j] + bias);
                    wgs[k * WGP + wv * 32 + 16 + l15] = (bf16_t)(acc[mt][1][j] + bias);
                }
            }
        }
    }
    __syncthreads();

    // ---- agg: thread = (wq, r, cp) -> 2 ch x 4 w; branchless; all-LDS ----
    float acc[2][4] = {};
#pragma unroll
    for (int di = 0; di < 7; ++di) {
        const int ri = r + di;
        float f0[12], f1[12];
        {
            const bf16_t* p0 = &fs2[ch0 * FSC2 + ri * FSR2 + w0];
            const bf16_t* p1 = p0 + FSC2;
#pragma unroll
            for (int qj = 0; qj < 3; ++qj) {
                const bf16x4 a = *(const bf16x4*)(p0 + qj * 4);
                const bf16x4 bq = *(const bf16x4*)(p1 + qj * 4);
#pragma unroll
                for (int j = 0; j < 4; ++j) {
                    f0[qj * 4 + j] = (float)a[j];
                    f1[qj * 4 + j] = (float)bq[j];
                }
            }
        }
        const bf16_t* wrow = &wgs[(di * 7) * WGP + r * 64 + w0];
#pragma unroll
        for (int dj = 0; dj < 7; ++dj) {
            const bf16x4 wb = *(const bf16x4*)(wrow + dj * WGP);
#pragma unroll
            for (int x = 0; x < 4; ++x) {
                const float wf = (float)wb[x];
                acc[0][x] = fmaf(wf, f0[x + dj + 1], acc[0][x]);
                acc[1][x] = fmaf(wf, f1[x + dj + 1], acc[1][x]);
            }
        }
    }

#pragma unroll
    for (int c = 0; c < 2; ++c) {
        const size_t ob = ((size_t)(b * 256 + g * 16 + ch0 + c) * 64 + h0 + r) * 64 + w0;
        float4 o;
        o.x = acc[c][0] + res[c].x; o.y = acc[c][1] + res[c].y;
        o.z = acc[c][2] + res[c].z; o.w = acc[c][3] + res[c].w;
        *(float4*)(out + ob) = o;
    }
}

extern "C" void kernel_launch(void* const* d_in, const int* in_sizes, int n_in,
                              void* d_out, int out_size, void* d_ws, size_t ws_size,
                              hipStream_t stream) {
    const float* feature = (const float*)d_in[0];
    const float* guide   = (const float*)d_in[1];
    const float* w1      = (const float*)d_in[2];
    const float* gamma   = (const float*)d_in[3];
    const float* beta    = (const float*)d_in[4];
    const float* mean    = (const float*)d_in[5];
    const float* var     = (const float*)d_in[6];
    const float* w2      = (const float*)d_in[7];
    const float* b2      = (const float*)d_in[8];
    float* out = (float*)d_out;

    bf16_t* xT = (bf16_t*)((char*)d_ws + XT_OFF);

    conv1_k<<<256, 256, 0, stream>>>(guide, w1, gamma, beta, mean, var, xT);
    fused_k<<<2048, 256, 0, stream>>>(xT, w2, b2, feature, out);
}

// Round 10
// 125.646 us; speedup vs baseline: 1.3603x; 1.3603x over previous
//
#include <hip/hip_runtime.h>

// B=4, C=256, CR=64, H=W=64, K=7, KK=49, GROUPS=16, GC=16
#define BN_EPS 1e-5f

typedef __bf16 bf16_t;
typedef __bf16 bf16x8 __attribute__((ext_vector_type(8)));
typedef __bf16 bf16x4 __attribute__((ext_vector_type(4)));
typedef __bf16 bf16x2 __attribute__((ext_vector_type(2)));
typedef float  floatx4 __attribute__((ext_vector_type(4)));

#define MFMA16(a, b, c) __builtin_amdgcn_mfma_f32_16x16x32_bf16((a), (b), (c), 0, 0, 0)

#define XT_OFF 0   // ws: xT = 16384 px x 64 ch bf16 = 2 MB

// ---------------------------------------------------------------------------
// K1 conv1: one block per (b,h). BN-fold in-block; LDS transpose of guide;
// MFMA x[64o][64p] = w1s . gTs; +bias, ReLU; store xT[bp][o] c-contiguous.
// ---------------------------------------------------------------------------
#define GTP 264
#define W1P 264

__global__ __launch_bounds__(256) void conv1_k(
    const float* __restrict__ guide, const float* __restrict__ w1,
    const float* __restrict__ gamma, const float* __restrict__ beta,
    const float* __restrict__ mean,  const float* __restrict__ var,
    bf16_t* __restrict__ xT)
{
    __shared__ __attribute__((aligned(16))) bf16_t gTs[64 * GTP];  // 33.8 KB
    __shared__ __attribute__((aligned(16))) bf16_t w1s[64 * W1P];  // 33.8 KB
    const int b = blockIdx.x >> 6, h = blockIdx.x & 63;
    const int t = threadIdx.x;

#pragma unroll
    for (int i = 0; i < 16; ++i) {
        const int idx = i * 256 + t;
        const int o = idx >> 6, cq = idx & 63;
        const float inv = gamma[o] * rsqrtf(var[o] + BN_EPS);
        const float4 v = *(const float4*)(w1 + o * 256 + cq * 4);
        bf16_t* d = &w1s[o * W1P + cq * 4];
        d[0] = (bf16_t)(v.x * inv); d[1] = (bf16_t)(v.y * inv);
        d[2] = (bf16_t)(v.z * inv); d[3] = (bf16_t)(v.w * inv);
    }
    const float* gsrc = guide + (size_t)b * 256 * 4096 + h * 64;
#pragma unroll
    for (int i = 0; i < 32; ++i) {
        const int idx = i * 256 + t;
        const int c2 = idx >> 6, p = idx & 63;
        const float g0 = gsrc[(size_t)(2 * c2) * 4096 + p];
        const float g1 = gsrc[(size_t)(2 * c2 + 1) * 4096 + p];
        bf16x2 pk; pk[0] = (bf16_t)g0; pk[1] = (bf16_t)g1;
        *(bf16x2*)&gTs[p * GTP + 2 * c2] = pk;
    }
    __syncthreads();

    const int wv = t >> 6, ln = t & 63, l15 = ln & 15, q = ln >> 4;
    floatx4 acc[4] = {};
    const bf16_t* ap = &w1s[(wv * 16 + l15) * W1P];
#pragma unroll
    for (int ks = 0; ks < 8; ++ks) {
        const bf16x8 a = *(const bf16x8*)(ap + ks * 32 + q * 8);
#pragma unroll
        for (int nt = 0; nt < 4; ++nt) {
            const bf16x8 bb = *(const bf16x8*)&gTs[(nt * 16 + l15) * GTP + ks * 32 + q * 8];
            acc[nt] = MFMA16(a, bb, acc[nt]);
        }
    }
    float bi[4];
#pragma unroll
    for (int j = 0; j < 4; ++j) {
        const int o = wv * 16 + q * 4 + j;
        const float iv = gamma[o] * rsqrtf(var[o] + BN_EPS);
        bi[j] = beta[o] - mean[o] * iv;
    }
#pragma unroll
    for (int nt = 0; nt < 4; ++nt) {
        const int p = nt * 16 + l15;
        bf16x4 v;
#pragma unroll
        for (int j = 0; j < 4; ++j) v[j] = (bf16_t)fmaxf(acc[nt][j] + bi[j], 0.f);
        *(bf16x4*)(xT + ((size_t)(b * 64 + h) * 64 + p) * 64 + wv * 16 + q * 4) = v;
    }
}

// ---------------------------------------------------------------------------
// K2 conv2+agg fused: block = (g, b, h-pair); blockIdx = (b*32+hp)*16 + g.
//  fs2: bf16 feature tile [16ch][8 rows][72] (pads zeroed) = 18.4 KB
//  wgs: bf16 dyn-weight tile [49k][136]                     = 13.3 KB
//  total 31.7 KB -> 5 blocks/CU via LDS (NO min-wave launch_bounds: R9's
//  (256,5) forced VGPR=48 -> scratch spills -> 174 MB HBM writes, 2.4x slower).
//  Residual float4s pre-loaded from global BEFORE the barrier (exact fp32).
// ---------------------------------------------------------------------------
#define FSR2 72    // bf16 row pitch: [4 pad][64 w][4 pad]
#define FSC2 576   // bf16 channel pitch = 8*72
#define WGP 136

__global__ __launch_bounds__(256) void fused_k(
    const bf16_t* __restrict__ xT, const float* __restrict__ w2,
    const float* __restrict__ b2,  const float* __restrict__ feat,
    float* __restrict__ out)
{
    __shared__ __attribute__((aligned(16))) bf16_t fs2[16 * FSC2];  // 18.4 KB
    __shared__ __attribute__((aligned(16))) bf16_t wgs[49 * WGP];   // 13.3 KB

    const int g = blockIdx.x & 15;
    const int rest = blockIdx.x >> 4;
    const int b = rest >> 5, hp = rest & 31;
    const int h0 = hp * 2;
    const int t = threadIdx.x;
    const int wv = t >> 6, ln = t & 63, l15 = ln & 15, q = ln >> 4;

    // agg-thread mapping (also used for residual preload)
    const int wq = t & 15, r = (t >> 4) & 1, cp = t >> 5;   // cp in [0,8)
    const int w0 = wq * 4;
    const int ch0 = cp * 2;

    // ---- residual preload (fp32 exact), latency hidden across barrier ----
    float4 res[2];
#pragma unroll
    for (int c = 0; c < 2; ++c)
        res[c] = *(const float4*)(feat + ((size_t)(b * 256 + g * 16 + ch0 + c) * 64 + h0 + r) * 64 + w0);

    // ---- stage fs2: 1152 units of bf16x8; unit j covers w in [8j-4, 8j+3] ----
#pragma unroll
    for (int i = 0; i < 5; ++i) {
        const int u = i * 256 + t;
        if (u < 1152) {
            const int c = u / 72, rem = u - c * 72;
            const int rr = rem / 9, j = rem - rr * 9;
            const int hh = h0 - 3 + rr;
            const float* rp = feat + ((size_t)(b * 256 + g * 16 + c) * 64 + hh) * 64;
            float4 lo = {0.f, 0.f, 0.f, 0.f}, hi = {0.f, 0.f, 0.f, 0.f};
            const bool hok = (hh >= 0) && (hh < 64);
            if (hok && j >= 1) lo = *(const float4*)(rp + 8 * j - 4);
            if (hok && j <= 7) hi = *(const float4*)(rp + 8 * j);
            bf16x8 v;
            v[0] = (bf16_t)lo.x; v[1] = (bf16_t)lo.y; v[2] = (bf16_t)lo.z; v[3] = (bf16_t)lo.w;
            v[4] = (bf16_t)hi.x; v[5] = (bf16_t)hi.y; v[6] = (bf16_t)hi.z; v[7] = (bf16_t)hi.w;
            *(bf16x8*)&fs2[c * FSC2 + rr * FSR2 + j * 8] = v;
        }
    }

    // ---- MFMA: wg[49 x 128] = w2[g] . xT ; A-frags cvt fp32->bf16 in regs ----
    {
        floatx4 acc[4][2] = {};
        const bf16_t* brow = xT + ((size_t)(b * 64 + h0) * 64 + wv * 32) * 64;
#pragma unroll
        for (int ks = 0; ks < 2; ++ks) {
            bf16x8 bfr[2];
            bfr[0] = *(const bf16x8*)(brow + l15 * 64 + ks * 32 + q * 8);
            bfr[1] = *(const bf16x8*)(brow + (16 + l15) * 64 + ks * 32 + q * 8);
#pragma unroll
            for (int mt = 0; mt < 4; ++mt) {
                int row = mt * 16 + l15; if (row > 48) row = 48;
                const float* wp = w2 + (size_t)(g * 49 + row) * 64 + ks * 32 + q * 8;
                const float4 a0 = *(const float4*)(wp);
                const float4 a1 = *(const float4*)(wp + 4);
                bf16x8 a;
                a[0] = (bf16_t)a0.x; a[1] = (bf16_t)a0.y; a[2] = (bf16_t)a0.z; a[3] = (bf16_t)a0.w;
                a[4] = (bf16_t)a1.x; a[5] = (bf16_t)a1.y; a[6] = (bf16_t)a1.z; a[7] = (bf16_t)a1.w;
                acc[mt][0] = MFMA16(a, bfr[0], acc[mt][0]);
                acc[mt][1] = MFMA16(a, bfr[1], acc[mt][1]);
            }
        }
#pragma unroll
        for (int mt = 0; mt < 4; ++mt) {
#pragma unroll
            for (int j = 0; j < 4; ++j) {
                const int k = mt * 16 + q * 4 + j;
                if (k < 49) {
                    const float bias = b2[g * 49 + k];
                    wgs[k * WGP + wv * 32 + l15]      = (bf16_t)(acc[mt][0][j] + bias);
                    wgs[k * WGP + wv * 32 + 16 + l15] = (bf16_t)(acc[mt][1][j] + bias);
                }
            }
        }
    }
    __syncthreads();

    // ---- agg: thread = (wq, r, cp) -> 2 ch x 4 w; branchless; all-LDS ----
    float acc[2][4] = {};
#pragma unroll
    for (int di = 0; di < 7; ++di) {
        const int ri = r + di;
        float f0[12], f1[12];
        {
            const bf16_t* p0 = &fs2[ch0 * FSC2 + ri * FSR2 + w0];
            const bf16_t* p1 = p0 + FSC2;
#pragma unroll
            for (int qj = 0; qj < 3; ++qj) {
                const bf16x4 a = *(const bf16x4*)(p0 + qj * 4);
                const bf16x4 bq = *(const bf16x4*)(p1 + qj * 4);
#pragma unroll
                for (int j = 0; j < 4; ++j) {
                    f0[qj * 4 + j] = (float)a[j];
                    f1[qj * 4 + j] = (float)bq[j];
                }
            }
        }
        const bf16_t* wrow = &wgs[(di * 7) * WGP + r * 64 + w0];
#pragma unroll
        for (int dj = 0; dj < 7; ++dj) {
            const bf16x4 wb = *(const bf16x4*)(wrow + dj * WGP);
#pragma unroll
            for (int x = 0; x < 4; ++x) {
                const float wf = (float)wb[x];
                acc[0][x] = fmaf(wf, f0[x + dj + 1], acc[0][x]);
                acc[1][x] = fmaf(wf, f1[x + dj + 1], acc[1][x]);
            }
        }
    }

#pragma unroll
    for (int c = 0; c < 2; ++c) {
        const size_t ob = ((size_t)(b * 256 + g * 16 + ch0 + c) * 64 + h0 + r) * 64 + w0;
        float4 o;
        o.x = acc[c][0] + res[c].x; o.y = acc[c][1] + res[c].y;
        o.z = acc[c][2] + res[c].z; o.w = acc[c][3] + res[c].w;
        *(float4*)(out + ob) = o;
    }
}

extern "C" void kernel_launch(void* const* d_in, const int* in_sizes, int n_in,
                              void* d_out, int out_size, void* d_ws, size_t ws_size,
                              hipStream_t stream) {
    const float* feature = (const float*)d_in[0];
    const float* guide   = (const float*)d_in[1];
    const float* w1      = (const float*)d_in[2];
    const float* gamma   = (const float*)d_in[3];
    const float* beta    = (const float*)d_in[4];
    const float* mean    = (const float*)d_in[5];
    const float* var     = (const float*)d_in[6];
    const float* w2      = (const float*)d_in[7];
    const float* b2      = (const float*)d_in[8];
    float* out = (float*)d_out;

    bf16_t* xT = (bf16_t*)((char*)d_ws + XT_OFF);

    conv1_k<<<256, 256, 0, stream>>>(guide, w1, gamma, beta, mean, var, xT);
    fused_k<<<2048, 256, 0, stream>>>(xT, w2, b2, feature, out);
}